// Round 8
// baseline (695.264 us; speedup 1.0000x reference)
//
#include <hip/hip_runtime.h>
#include <hip/hip_bf16.h>
#include <stdint.h>

typedef __bf16 bf16x8 __attribute__((ext_vector_type(8)));
typedef float  f32x4  __attribute__((ext_vector_type(4)));

#define SEQ   2048
#define DIMV  1024
#define HEADS 16
#define HDIM  64
#define KD    1024

// 0.125 (HEAD_DIM^-0.5) * log2(e)
#define SCL 0.1803368801111204f
// defer-max threshold in raw-score units: THRRAW*SCL = 8 -> P <= 2^8
#define THRRAW 44.36f

static __device__ __forceinline__ unsigned short f2bf(float f) {
  union { float f; unsigned u; } v; v.f = f;
  unsigned r = (v.u + 0x7fffu + ((v.u >> 16) & 1u)) >> 16;
  return (unsigned short)r;
}

// ---------------- fp32 -> bf16 convert (vectorized) ----------------
__global__ void cvt_kernel(const float* __restrict__ src,
                           ushort4* __restrict__ dst, int n4) {
  int i = blockIdx.x * 256 + threadIdx.x;
  if (i >= n4) return;
  float4 v = reinterpret_cast<const float4*>(src)[i];
  ushort4 o;
  o.x = f2bf(v.x); o.y = f2bf(v.y); o.z = f2bf(v.z); o.w = f2bf(v.w);
  dst[i] = o;
}

// ---------------- async global->LDS 16B ----------------
static __device__ __forceinline__ void gload_lds16(const unsigned short* g,
                                                   unsigned short* l) {
  __builtin_amdgcn_global_load_lds(
      (const __attribute__((address_space(1))) unsigned int*)g,
      (__attribute__((address_space(3))) unsigned int*)l, 16, 0, 0);
}

// ---------------- GEMM: C[M,N] = A[M,K] * B[N,K]^T ----------------
template <int MODE>
__global__ __launch_bounds__(256) void gemm_bt(
    const unsigned short* __restrict__ A,
    const unsigned short* __restrict__ B,
    void* __restrict__ Cv,
    const float* __restrict__ bias) {
  __shared__ unsigned short As[128 * 32];
  __shared__ unsigned short Bs[128 * 32];
  const int t = threadIdx.x;
  const int lane = t & 63, wave = t >> 6;
  const int fr = lane & 15, fq = lane >> 4;
  const int m0 = blockIdx.x * 128, n0 = blockIdx.y * 128;
  const int wm0 = (wave >> 1) * 64, wn0 = (wave & 1) * 64;

  const int srow = wave * 16 + (lane >> 2);
  const int scol = (lane & 3) * 8;
  const unsigned short* gA = A + (size_t)(m0 + srow) * KD + scol;
  const unsigned short* gB = B + (size_t)(n0 + srow) * KD + scol;
  unsigned short* lA = &As[srow * 32 + scol];
  unsigned short* lB = &Bs[srow * 32 + scol];

  f32x4 acc[4][4];
#pragma unroll
  for (int i = 0; i < 4; ++i)
#pragma unroll
    for (int j = 0; j < 4; ++j) acc[i][j] = (f32x4){0.f, 0.f, 0.f, 0.f};

  for (int k0 = 0;;) {
    gload_lds16(gA + k0, lA);
    gload_lds16(gA + (size_t)64 * KD + k0, lA + 64 * 32);
    gload_lds16(gB + k0, lB);
    gload_lds16(gB + (size_t)64 * KD + k0, lB + 64 * 32);
    __syncthreads();

    bf16x8 af[4], bfv[4];
#pragma unroll
    for (int mi = 0; mi < 4; ++mi)
      af[mi] = *(const bf16x8*)&As[(wm0 + mi * 16 + fr) * 32 + fq * 8];
#pragma unroll
    for (int nj = 0; nj < 4; ++nj)
      bfv[nj] = *(const bf16x8*)&Bs[(wn0 + nj * 16 + fr) * 32 + fq * 8];
#pragma unroll
    for (int mi = 0; mi < 4; ++mi)
#pragma unroll
      for (int nj = 0; nj < 4; ++nj)
        acc[mi][nj] = __builtin_amdgcn_mfma_f32_16x16x32_bf16(
            af[mi], bfv[nj], acc[mi][nj], 0, 0, 0);

    k0 += 32;
    if (k0 >= KD) break;
    __syncthreads();
  }

#pragma unroll
  for (int mi = 0; mi < 4; ++mi)
#pragma unroll
    for (int nj = 0; nj < 4; ++nj)
#pragma unroll
      for (int r = 0; r < 4; ++r) {
        const int gr = m0 + wm0 + mi * 16 + fq * 4 + r;
        const int gc = n0 + wn0 + nj * 16 + fr;
        const float v = acc[mi][nj][r];
        if (MODE == 0) {
          size_t off = (((size_t)(gr >> 11) * HEADS + (gc >> 6)) * SEQ +
                        (gr & 2047)) * HDIM + (gc & 63);
          ((unsigned short*)Cv)[off] = f2bf(v);
        } else if (MODE == 1) {
          size_t off = (size_t)(gc >> 11) * (DIMV * SEQ) + (size_t)gr * SEQ +
                       (gc & 2047);
          ((unsigned short*)Cv)[off] = f2bf(v);
        } else {
          ((float*)Cv)[(size_t)gr * DIMV + gc] = v + bias[gc];
        }
      }
}

// ---------------- flash attention (16 q-rows/wave, dbuf-P, XCD-local) -----
// grid 2048 (1D): xcd = wg&7 owns 8 bh (all 32 q-tiles) -> K/V = 4MB, L2-fit.
// 4 waves x 16 q-rows = 64 rows/block. Barrier-free; P double-buffered by
// tile parity so iteration t+1's P-write never waits on iteration t's P-read.
// Swapped QK^T: lane holds S[q=fr][k=nj*16+fq*4+r] -> lane-local softmax.
// PV = mfma(P, V): O[q=fq*4+r][d=fr].
__global__ __launch_bounds__(256) void attn_kernel(
    const unsigned short* __restrict__ q, const unsigned short* __restrict__ k,
    const unsigned short* __restrict__ vt, unsigned short* __restrict__ ao) {
  __shared__ unsigned short Pl[4][2][16 * 64];  // [wave][parity], swizzled
  const int t = threadIdx.x, lane = t & 63, wave = t >> 6;
  const int fr = lane & 15, fq = lane >> 4;
  const int wg = blockIdx.x;
  const int xcd = wg & 7, idx = wg >> 3;
  const int bh = (xcd << 3) | (idx >> 5);   // 8 bh per XCD
  const int qt = idx & 31;                  // 32 q-tiles of 64 rows
  const int b = bh >> 4, h = bh & 15;
  const int qrow0 = qt * 64 + wave * 16;

  const unsigned short* qp = q + ((size_t)bh * SEQ + qrow0) * HDIM;
  const unsigned short* kp = k + (size_t)bh * SEQ * HDIM;
  const unsigned short* vp = vt + (size_t)b * (DIMV * SEQ) + (size_t)(h * HDIM) * SEQ;

  bf16x8 qf[2];
#pragma unroll
  for (int kc = 0; kc < 2; ++kc)
    qf[kc] = *(const bf16x8*)(qp + (size_t)fr * HDIM + kc * 32 + fq * 8);

  f32x4 oacc[4];
#pragma unroll
  for (int dj = 0; dj < 4; ++dj) oacc[dj] = (f32x4){0.f, 0.f, 0.f, 0.f};
  float m_s = -1e30f, lrow = 0.f;
  float m_o[4];
#pragma unroll
  for (int r = 0; r < 4; ++r) m_o[r] = -1e30f;

  for (int kb = 0; kb < SEQ; kb += 64) {
    char* plw = (char*)&Pl[wave][(kb >> 6) & 1][0];
    // ---- K and V register loads issued up front (L2-resident) ----
    bf16x8 kf[4][2], vf[4][2];
#pragma unroll
    for (int nj = 0; nj < 4; ++nj)
#pragma unroll
      for (int kc = 0; kc < 2; ++kc)
        kf[nj][kc] = *(const bf16x8*)(kp + (size_t)(kb + nj * 16 + fr) * HDIM + kc * 32 + fq * 8);
#pragma unroll
    for (int dj = 0; dj < 4; ++dj)
#pragma unroll
      for (int kc = 0; kc < 2; ++kc)
        vf[dj][kc] = *(const bf16x8*)(vp + (size_t)(dj * 16 + fr) * SEQ + kb + kc * 32 + fq * 8);

    // ---- S = mfma(K, Q): lane holds S[q=fr][k=nj*16+fq*4+r] ----
    f32x4 sacc[4];
#pragma unroll
    for (int nj = 0; nj < 4; ++nj) sacc[nj] = (f32x4){0.f, 0.f, 0.f, 0.f};
    __builtin_amdgcn_s_setprio(1);
#pragma unroll
    for (int nj = 0; nj < 4; ++nj)
#pragma unroll
      for (int kc = 0; kc < 2; ++kc)
        sacc[nj] = __builtin_amdgcn_mfma_f32_16x16x32_bf16(
            kf[nj][kc], qf[kc], sacc[nj], 0, 0, 0);
    __builtin_amdgcn_s_setprio(0);

    // ---- online softmax, lane-local per q-row ----
    float t0 = fmaxf(fmaxf(sacc[0][0], sacc[0][1]), fmaxf(sacc[0][2], sacc[0][3]));
    float t1 = fmaxf(fmaxf(sacc[1][0], sacc[1][1]), fmaxf(sacc[1][2], sacc[1][3]));
    float t2 = fmaxf(fmaxf(sacc[2][0], sacc[2][1]), fmaxf(sacc[2][2], sacc[2][3]));
    float t3 = fmaxf(fmaxf(sacc[3][0], sacc[3][1]), fmaxf(sacc[3][2], sacc[3][3]));
    float tmax = fmaxf(fmaxf(t0, t1), fmaxf(t2, t3));
    tmax = fmaxf(tmax, __shfl_xor(tmax, 16));
    tmax = fmaxf(tmax, __shfl_xor(tmax, 32));

    if (__any(tmax > m_s + THRRAW)) {   // defer-max (T13)
      const float mnew = fmaxf(m_s, tmax);
      lrow *= exp2f((m_s - mnew) * SCL);
      m_s = mnew;
#pragma unroll
      for (int r = 0; r < 4; ++r) {
        const float t_o = __shfl(tmax, ((lane >> 4) << 2) + r);
        const float mo_new = fmaxf(m_o[r], t_o);
        const float fo = exp2f((m_o[r] - mo_new) * SCL);
        m_o[r] = mo_new;
#pragma unroll
        for (int dj = 0; dj < 4; ++dj) oacc[dj][r] *= fo;
      }
    }

    const float nm = m_s * SCL;
    float ls = 0.f;
#pragma unroll
    for (int nj = 0; nj < 4; ++nj) {
      float p0 = exp2f(__builtin_fmaf(sacc[nj][0], SCL, -nm));
      float p1 = exp2f(__builtin_fmaf(sacc[nj][1], SCL, -nm));
      float p2 = exp2f(__builtin_fmaf(sacc[nj][2], SCL, -nm));
      float p3 = exp2f(__builtin_fmaf(sacc[nj][3], SCL, -nm));
      ls += (p0 + p1) + (p2 + p3);
      unsigned lo = (unsigned)f2bf(p0) | ((unsigned)f2bf(p1) << 16);
      unsigned hi = (unsigned)f2bf(p2) | ((unsigned)f2bf(p3) << 16);
      const int colb = (nj * 16 + fq * 4) * 2;
      *(uint2*)(plw + ((fr * 128 + colb) ^ ((fr & 7) << 4))) = make_uint2(lo, hi);
    }
    lrow += ls;

    // ---- O += mfma(P, V): O[q=fq*4+r][d=fr] ----
    bf16x8 pf[2];
#pragma unroll
    for (int kc = 0; kc < 2; ++kc)
      pf[kc] = *(const bf16x8*)(plw + ((fr * 128 + (kc * 32 + fq * 8) * 2) ^ ((fr & 7) << 4)));
    __builtin_amdgcn_s_setprio(1);
#pragma unroll
    for (int dj = 0; dj < 4; ++dj)
#pragma unroll
      for (int kc = 0; kc < 2; ++kc)
        oacc[dj] = __builtin_amdgcn_mfma_f32_16x16x32_bf16(
            pf[kc], vf[dj][kc], oacc[dj], 0, 0, 0);
    __builtin_amdgcn_s_setprio(0);
  }

  // ---- final l reduce + redistribute to O-layout, normalize + store ----
  float lt = lrow;
  lt += __shfl_xor(lt, 16);
  lt += __shfl_xor(lt, 32);
#pragma unroll
  for (int r = 0; r < 4; ++r) {
    const float l_o = __shfl(lt, ((lane >> 4) << 2) + r);
    const float inv = 1.f / l_o;
    const size_t grow = (size_t)b * SEQ + qt * 64 + wave * 16 + fq * 4 + r;
#pragma unroll
    for (int dj = 0; dj < 4; ++dj) {
      const int col = h * HDIM + dj * 16 + fr;
      ao[grow * DIMV + col] = f2bf(oacc[dj][r] * inv);
    }
  }
}

// ---------------- launch ----------------
extern "C" void kernel_launch(void* const* d_in, const int* in_sizes, int n_in,
                              void* d_out, int out_size, void* d_ws, size_t ws_size,
                              hipStream_t stream) {
  const float* x   = (const float*)d_in[0];
  const float* ctx = (const float*)d_in[1];
  const float* Wq  = (const float*)d_in[2];
  const float* Wk  = (const float*)d_in[3];
  const float* Wv  = (const float*)d_in[4];
  const float* Wo  = (const float*)d_in[5];
  const float* bo  = (const float*)d_in[6];

  char* ws = (char*)d_ws;
  unsigned short* xb  = (unsigned short*)(ws);              // 16MB, reused as ao
  unsigned short* cb  = (unsigned short*)(ws + 16777216);   // 16MB
  unsigned short* wqb = (unsigned short*)(ws + 33554432);   // 2MB
  unsigned short* wkb = (unsigned short*)(ws + 35651584);
  unsigned short* wvb = (unsigned short*)(ws + 37748736);
  unsigned short* wob = (unsigned short*)(ws + 39845888);
  unsigned short* qb  = (unsigned short*)(ws + 41943040);   // 16MB
  unsigned short* kb  = (unsigned short*)(ws + 58720256);   // 16MB
  unsigned short* vtb = (unsigned short*)(ws + 75497472);   // 16MB

  auto cvt = [&](const float* s, unsigned short* d, int n) {
    int n4 = n >> 2;
    cvt_kernel<<<(n4 + 255) / 256, 256, 0, stream>>>(s, (ushort4*)d, n4);
  };
  const int NTOK = 4 * SEQ;  // 8192
  cvt(x,   xb,  NTOK * DIMV);
  cvt(ctx, cb,  NTOK * DIMV);
  cvt(Wq,  wqb, DIMV * DIMV);
  cvt(Wk,  wkb, DIMV * DIMV);
  cvt(Wv,  wvb, DIMV * DIMV);
  cvt(Wo,  wob, DIMV * DIMV);

  gemm_bt<0><<<dim3(64, 8), 256, 0, stream>>>(xb, wqb, qb, nullptr);
  gemm_bt<0><<<dim3(64, 8), 256, 0, stream>>>(cb, wkb, kb, nullptr);
  gemm_bt<1><<<dim3(8, 64), 256, 0, stream>>>(wvb, cb, vtb, nullptr);

  unsigned short* aob = xb;
  attn_kernel<<<dim3(2048), 256, 0, stream>>>(qb, kb, vtb, aob);

  gemm_bt<2><<<dim3(64, 8), 256, 0, stream>>>(aob, wob, (float*)d_out, bo);
}

// Round 9
// 406.544 us; speedup vs baseline: 1.7102x; 1.7102x over previous
//
#include <hip/hip_runtime.h>
#include <hip/hip_bf16.h>
#include <stdint.h>

typedef __bf16 bf16x8 __attribute__((ext_vector_type(8)));
typedef float  f32x4  __attribute__((ext_vector_type(4)));

#define SEQ   2048
#define DIMV  1024
#define HEADS 16
#define HDIM  64
#define KD    1024

// 0.125 (HEAD_DIM^-0.5) * log2(e)
#define SCL 0.1803368801111204f
// defer-max threshold in raw-score units: THRRAW*SCL = 8 -> P <= 2^8
#define THRRAW 44.36f

static __device__ __forceinline__ unsigned short f2bf(float f) {
  union { float f; unsigned u; } v; v.f = f;
  unsigned r = (v.u + 0x7fffu + ((v.u >> 16) & 1u)) >> 16;
  return (unsigned short)r;
}

// ---------------- fp32 -> bf16 convert (vectorized) ----------------
__global__ void cvt_kernel(const float* __restrict__ src,
                           ushort4* __restrict__ dst, int n4) {
  int i = blockIdx.x * 256 + threadIdx.x;
  if (i >= n4) return;
  float4 v = reinterpret_cast<const float4*>(src)[i];
  ushort4 o;
  o.x = f2bf(v.x); o.y = f2bf(v.y); o.z = f2bf(v.z); o.w = f2bf(v.w);
  dst[i] = o;
}

// ---------------- async global->LDS 16B ----------------
static __device__ __forceinline__ void gload_lds16(const unsigned short* g,
                                                   unsigned short* l) {
  __builtin_amdgcn_global_load_lds(
      (const __attribute__((address_space(1))) unsigned int*)g,
      (__attribute__((address_space(3))) unsigned int*)l, 16, 0, 0);
}

// ---------------- GEMM: C[M,N] = A[M,K] * B[N,K]^T ----------------
template <int MODE>
__global__ __launch_bounds__(256) void gemm_bt(
    const unsigned short* __restrict__ A,
    const unsigned short* __restrict__ B,
    void* __restrict__ Cv,
    const float* __restrict__ bias) {
  __shared__ unsigned short As[128 * 32];
  __shared__ unsigned short Bs[128 * 32];
  const int t = threadIdx.x;
  const int lane = t & 63, wave = t >> 6;
  const int fr = lane & 15, fq = lane >> 4;
  const int m0 = blockIdx.x * 128, n0 = blockIdx.y * 128;
  const int wm0 = (wave >> 1) * 64, wn0 = (wave & 1) * 64;

  const int srow = wave * 16 + (lane >> 2);
  const int scol = (lane & 3) * 8;
  const unsigned short* gA = A + (size_t)(m0 + srow) * KD + scol;
  const unsigned short* gB = B + (size_t)(n0 + srow) * KD + scol;
  unsigned short* lA = &As[srow * 32 + scol];
  unsigned short* lB = &Bs[srow * 32 + scol];

  f32x4 acc[4][4];
#pragma unroll
  for (int i = 0; i < 4; ++i)
#pragma unroll
    for (int j = 0; j < 4; ++j) acc[i][j] = (f32x4){0.f, 0.f, 0.f, 0.f};

  for (int k0 = 0;;) {
    gload_lds16(gA + k0, lA);
    gload_lds16(gA + (size_t)64 * KD + k0, lA + 64 * 32);
    gload_lds16(gB + k0, lB);
    gload_lds16(gB + (size_t)64 * KD + k0, lB + 64 * 32);
    __syncthreads();

    bf16x8 af[4], bfv[4];
#pragma unroll
    for (int mi = 0; mi < 4; ++mi)
      af[mi] = *(const bf16x8*)&As[(wm0 + mi * 16 + fr) * 32 + fq * 8];
#pragma unroll
    for (int nj = 0; nj < 4; ++nj)
      bfv[nj] = *(const bf16x8*)&Bs[(wn0 + nj * 16 + fr) * 32 + fq * 8];
#pragma unroll
    for (int mi = 0; mi < 4; ++mi)
#pragma unroll
      for (int nj = 0; nj < 4; ++nj)
        acc[mi][nj] = __builtin_amdgcn_mfma_f32_16x16x32_bf16(
            af[mi], bfv[nj], acc[mi][nj], 0, 0, 0);

    k0 += 32;
    if (k0 >= KD) break;
    __syncthreads();
  }

#pragma unroll
  for (int mi = 0; mi < 4; ++mi)
#pragma unroll
    for (int nj = 0; nj < 4; ++nj)
#pragma unroll
      for (int r = 0; r < 4; ++r) {
        const int gr = m0 + wm0 + mi * 16 + fq * 4 + r;
        const int gc = n0 + wn0 + nj * 16 + fr;
        const float v = acc[mi][nj][r];
        if (MODE == 0) {
          size_t off = (((size_t)(gr >> 11) * HEADS + (gc >> 6)) * SEQ +
                        (gr & 2047)) * HDIM + (gc & 63);
          ((unsigned short*)Cv)[off] = f2bf(v);
        } else if (MODE == 1) {
          size_t off = (size_t)(gc >> 11) * (DIMV * SEQ) + (size_t)gr * SEQ +
                       (gc & 2047);
          ((unsigned short*)Cv)[off] = f2bf(v);
        } else {
          ((float*)Cv)[(size_t)gr * DIMV + gc] = v + bias[gc];
        }
      }
}

// ---------------- flash attention (block-shared K/V in LDS, dbuf) ---------
// grid 512: xcd = wg&7 owns 8 bh x 8 q-tiles -> K/V = 4MB, L2-fit.
// 8 waves x 32 q-rows = 256 rows/block; K,V tiles staged ONCE per block into
// double-buffered, XOR-swizzled LDS (global_load_lds, pre-swizzled source per
// G21) -> per-CU K/V VMEM traffic 8x lower than per-wave register streaming.
// Swapped QK^T: lane holds S[q=mi*16+fr][k=nj*16+fq*4+r] -> lane-local softmax.
// PV = mfma(P, V): O[q=mi*16+fq*4+r][d=dj*16+fr].
__global__ __launch_bounds__(512) void attn_kernel(
    const unsigned short* __restrict__ q, const unsigned short* __restrict__ k,
    const unsigned short* __restrict__ vt, unsigned short* __restrict__ ao) {
  __shared__ unsigned short Ks[2][64 * 64];  // 16 KB, swizzled rows
  __shared__ unsigned short Vs[2][64 * 64];  // 16 KB, swizzled rows
  __shared__ unsigned short Pl[8][32 * 64];  // 32 KB, per-wave P
  const int t = threadIdx.x, lane = t & 63, wave = t >> 6;
  const int fr = lane & 15, fq = lane >> 4;
  const int wg = blockIdx.x;
  const int xcd = wg & 7, idx = wg >> 3;
  const int bh = (xcd << 3) | (idx >> 3);   // 8 bh per XCD
  const int qt = idx & 7;                   // 8 q-tiles of 256 rows
  const int b = bh >> 4, h = bh & 15;
  const int qrow0 = qt * 256 + wave * 32;

  const unsigned short* qp = q + ((size_t)bh * SEQ + qrow0) * HDIM;
  const unsigned short* kp = k + (size_t)bh * SEQ * HDIM;
  const unsigned short* vp = vt + (size_t)b * (DIMV * SEQ) + (size_t)(h * HDIM) * SEQ;
  char* plw = (char*)&Pl[wave][0];

  // staging map (512 threads, one 8KB tile per issue):
  // thread t -> LDS bytes [t*16, t*16+16) ; LDS row = t>>3, col byte (t&7)*16.
  // LDS[row][c] must hold global[row][c ^ ((row&7)<<4)] (read-side XOR), so
  // source col byte = ((t&7)*16) ^ ((row&7)<<4)   [involution, 16B-aligned]
  const int srow = t >> 3;
  const int scolb = ((t & 7) << 4) ^ ((srow & 7) << 4);

  bf16x8 qf[2][2];
#pragma unroll
  for (int mi = 0; mi < 2; ++mi)
#pragma unroll
    for (int kc = 0; kc < 2; ++kc)
      qf[mi][kc] = *(const bf16x8*)(qp + (size_t)(mi * 16 + fr) * HDIM + kc * 32 + fq * 8);

  f32x4 oacc[2][4];
  float m_s[2], m_o[2][4], lrow[2];
#pragma unroll
  for (int mi = 0; mi < 2; ++mi) {
#pragma unroll
    for (int dj = 0; dj < 4; ++dj) oacc[mi][dj] = (f32x4){0.f, 0.f, 0.f, 0.f};
    m_s[mi] = -1e30f; lrow[mi] = 0.f;
#pragma unroll
    for (int r = 0; r < 4; ++r) m_o[mi][r] = -1e30f;
  }

  // prologue: stage tile 0 (K rows contiguous 128B; V rows stride SEQ)
  gload_lds16(kp + (size_t)srow * HDIM + (scolb >> 1), &Ks[0][t * 8]);
  gload_lds16(vp + (size_t)srow * SEQ + (scolb >> 1), &Vs[0][t * 8]);
  __syncthreads();

  int cur = 0;
  for (int kb = 0; kb < SEQ; kb += 64, cur ^= 1) {
    // stage next tile into other buffer (drained by end-of-iter barrier)
    if (kb + 64 < SEQ) {
      gload_lds16(kp + (size_t)(kb + 64 + srow) * HDIM + (scolb >> 1),
                  &Ks[cur ^ 1][t * 8]);
      gload_lds16(vp + (size_t)srow * SEQ + (kb + 64) + (scolb >> 1),
                  &Vs[cur ^ 1][t * 8]);
    }

    const char* kls = (const char*)&Ks[cur][0];
    const char* vls = (const char*)&Vs[cur][0];

    // ---- S = mfma(K, Q): lane holds S[q=mi*16+fr][k=nj*16+fq*4+r] ----
    f32x4 sacc[2][4];
#pragma unroll
    for (int mi = 0; mi < 2; ++mi)
#pragma unroll
      for (int nj = 0; nj < 4; ++nj) sacc[mi][nj] = (f32x4){0.f, 0.f, 0.f, 0.f};
#pragma unroll
    for (int kc = 0; kc < 2; ++kc) {
      bf16x8 kf[4];
#pragma unroll
      for (int nj = 0; nj < 4; ++nj)
        kf[nj] = *(const bf16x8*)(kls + (nj * 16 + fr) * 128 +
                                  ((kc * 64 + fq * 16) ^ ((fr & 7) << 4)));
      __builtin_amdgcn_s_setprio(1);
#pragma unroll
      for (int mi = 0; mi < 2; ++mi)
#pragma unroll
        for (int nj = 0; nj < 4; ++nj)
          sacc[mi][nj] = __builtin_amdgcn_mfma_f32_16x16x32_bf16(
              kf[nj], qf[mi][kc], sacc[mi][nj], 0, 0, 0);
      __builtin_amdgcn_s_setprio(0);
    }

    // ---- online softmax: lane-local per q-row ----
#pragma unroll
    for (int mi = 0; mi < 2; ++mi) {
      float tmax = -1e30f;
#pragma unroll
      for (int nj = 0; nj < 4; ++nj)
#pragma unroll
        for (int r = 0; r < 4; ++r) tmax = fmaxf(tmax, sacc[mi][nj][r]);
      tmax = fmaxf(tmax, __shfl_xor(tmax, 16));
      tmax = fmaxf(tmax, __shfl_xor(tmax, 32));

      if (__any(tmax > m_s[mi] + THRRAW)) {   // defer-max (T13)
        const float mnew = fmaxf(m_s[mi], tmax);
        lrow[mi] *= exp2f((m_s[mi] - mnew) * SCL);
        m_s[mi] = mnew;
#pragma unroll
        for (int r = 0; r < 4; ++r) {
          const float t_o = __shfl(tmax, ((lane >> 4) << 2) + r);
          const float mo_new = fmaxf(m_o[mi][r], t_o);
          const float fo = exp2f((m_o[mi][r] - mo_new) * SCL);
          m_o[mi][r] = mo_new;
#pragma unroll
          for (int dj = 0; dj < 4; ++dj) oacc[mi][dj][r] *= fo;
        }
      }

      const float nm = m_s[mi] * SCL;
      float ls = 0.f;
      const int row = mi * 16 + fr;
#pragma unroll
      for (int nj = 0; nj < 4; ++nj) {
        float p0 = exp2f(__builtin_fmaf(sacc[mi][nj][0], SCL, -nm));
        float p1 = exp2f(__builtin_fmaf(sacc[mi][nj][1], SCL, -nm));
        float p2 = exp2f(__builtin_fmaf(sacc[mi][nj][2], SCL, -nm));
        float p3 = exp2f(__builtin_fmaf(sacc[mi][nj][3], SCL, -nm));
        ls += (p0 + p1) + (p2 + p3);
        unsigned lo = (unsigned)f2bf(p0) | ((unsigned)f2bf(p1) << 16);
        unsigned hi = (unsigned)f2bf(p2) | ((unsigned)f2bf(p3) << 16);
        const int colb = (nj * 16 + fq * 4) * 2;
        *(uint2*)(plw + ((row * 128 + colb) ^ ((row & 7) << 4))) =
            make_uint2(lo, hi);
      }
      lrow[mi] += ls;
    }

    // ---- O += mfma(P, V): O[q=mi*16+fq*4+r][d=dj*16+fr] ----
    bf16x8 pf[2][2];
#pragma unroll
    for (int mi = 0; mi < 2; ++mi)
#pragma unroll
      for (int kc = 0; kc < 2; ++kc) {
        const int row = mi * 16 + fr, colb = (kc * 32 + fq * 8) * 2;
        pf[mi][kc] = *(const bf16x8*)(plw + ((row * 128 + colb) ^ ((row & 7) << 4)));
      }
#pragma unroll
    for (int kc = 0; kc < 2; ++kc) {
      bf16x8 vf[4];
#pragma unroll
      for (int dj = 0; dj < 4; ++dj)
        vf[dj] = *(const bf16x8*)(vls + (dj * 16 + fr) * 128 +
                                  ((kc * 64 + fq * 16) ^ ((fr & 7) << 4)));
      __builtin_amdgcn_s_setprio(1);
#pragma unroll
      for (int mi = 0; mi < 2; ++mi)
#pragma unroll
        for (int dj = 0; dj < 4; ++dj)
          oacc[mi][dj] = __builtin_amdgcn_mfma_f32_16x16x32_bf16(
              pf[mi][kc], vf[dj], oacc[mi][dj], 0, 0, 0);
      __builtin_amdgcn_s_setprio(0);
    }

    __syncthreads();  // next tile staged; all reads of Ks/Vs[cur] done
  }

  // ---- final l reduce + redistribute to O-layout, normalize + store ----
#pragma unroll
  for (int mi = 0; mi < 2; ++mi) {
    float lt = lrow[mi];
    lt += __shfl_xor(lt, 16);
    lt += __shfl_xor(lt, 32);
#pragma unroll
    for (int r = 0; r < 4; ++r) {
      const float l_o = __shfl(lt, ((lane >> 4) << 2) + r);
      const float inv = 1.f / l_o;
      const size_t grow = (size_t)b * SEQ + qt * 256 + wave * 32 +
                          mi * 16 + fq * 4 + r;
#pragma unroll
      for (int dj = 0; dj < 4; ++dj) {
        const int col = h * HDIM + dj * 16 + fr;
        ao[grow * DIMV + col] = f2bf(oacc[mi][dj][r] * inv);
      }
    }
  }
}

// ---------------- launch ----------------
extern "C" void kernel_launch(void* const* d_in, const int* in_sizes, int n_in,
                              void* d_out, int out_size, void* d_ws, size_t ws_size,
                              hipStream_t stream) {
  const float* x   = (const float*)d_in[0];
  const float* ctx = (const float*)d_in[1];
  const float* Wq  = (const float*)d_in[2];
  const float* Wk  = (const float*)d_in[3];
  const float* Wv  = (const float*)d_in[4];
  const float* Wo  = (const float*)d_in[5];
  const float* bo  = (const float*)d_in[6];

  char* ws = (char*)d_ws;
  unsigned short* xb  = (unsigned short*)(ws);              // 16MB, reused as ao
  unsigned short* cb  = (unsigned short*)(ws + 16777216);   // 16MB
  unsigned short* wqb = (unsigned short*)(ws + 33554432);   // 2MB
  unsigned short* wkb = (unsigned short*)(ws + 35651584);
  unsigned short* wvb = (unsigned short*)(ws + 37748736);
  unsigned short* wob = (unsigned short*)(ws + 39845888);
  unsigned short* qb  = (unsigned short*)(ws + 41943040);   // 16MB
  unsigned short* kb  = (unsigned short*)(ws + 58720256);   // 16MB
  unsigned short* vtb = (unsigned short*)(ws + 75497472);   // 16MB

  auto cvt = [&](const float* s, unsigned short* d, int n) {
    int n4 = n >> 2;
    cvt_kernel<<<(n4 + 255) / 256, 256, 0, stream>>>(s, (ushort4*)d, n4);
  };
  const int NTOK = 4 * SEQ;  // 8192
  cvt(x,   xb,  NTOK * DIMV);
  cvt(ctx, cb,  NTOK * DIMV);
  cvt(Wq,  wqb, DIMV * DIMV);
  cvt(Wk,  wkb, DIMV * DIMV);
  cvt(Wv,  wvb, DIMV * DIMV);
  cvt(Wo,  wob, DIMV * DIMV);

  gemm_bt<0><<<dim3(64, 8), 256, 0, stream>>>(xb, wqb, qb, nullptr);
  gemm_bt<0><<<dim3(64, 8), 256, 0, stream>>>(cb, wkb, kb, nullptr);
  gemm_bt<1><<<dim3(8, 64), 256, 0, stream>>>(wvb, cb, vtb, nullptr);

  unsigned short* aob = xb;
  attn_kernel<<<dim3(512), 512, 0, stream>>>(qb, kb, vtb, aob);

  gemm_bt<2><<<dim3(64, 8), 256, 0, stream>>>(aob, wob, (float*)d_out, bo);
}

// Round 11
// 381.678 us; speedup vs baseline: 1.8216x; 1.0651x over previous
//
#include <hip/hip_runtime.h>
#include <hip/hip_bf16.h>
#include <stdint.h>

typedef __bf16 bf16x8 __attribute__((ext_vector_type(8)));
typedef __bf16 bf16x2v __attribute__((ext_vector_type(2)));
typedef float  f32x4  __attribute__((ext_vector_type(4)));

#define SEQ   2048
#define DIMV  1024
#define HEADS 16
#define HDIM  64
#define KD    1024

// 0.125 (HEAD_DIM^-0.5) * log2(e)
#define SCL 0.1803368801111204f
// defer-max threshold in raw-score units: THRRAW*SCL = 8 -> P <= 2^8
#define THRRAW 44.36f

static __device__ __forceinline__ unsigned short f2bf(float f) {
  union { float f; unsigned u; } v; v.f = f;
  unsigned r = (v.u + 0x7fffu + ((v.u >> 16) & 1u)) >> 16;
  return (unsigned short)r;
}

// native HW bf16 convert (compiler fuses pairs into v_cvt_pk_bf16_f32)
static __device__ __forceinline__ unsigned short bfc(float f) {
  __bf16 b = (__bf16)f;
  unsigned short u;
  __builtin_memcpy(&u, &b, 2);
  return u;
}
static __device__ __forceinline__ unsigned pk2(float a, float b) {
  bf16x2v v = {(__bf16)a, (__bf16)b};
  unsigned r;
  __builtin_memcpy(&r, &v, 4);
  return r;
}

// ---------------- fp32 -> bf16 convert (vectorized) ----------------
__global__ void cvt_kernel(const float* __restrict__ src,
                           ushort4* __restrict__ dst, int n4) {
  int i = blockIdx.x * 256 + threadIdx.x;
  if (i >= n4) return;
  float4 v = reinterpret_cast<const float4*>(src)[i];
  ushort4 o;
  o.x = f2bf(v.x); o.y = f2bf(v.y); o.z = f2bf(v.z); o.w = f2bf(v.w);
  dst[i] = o;
}

// ---------------- async global->LDS 16B ----------------
static __device__ __forceinline__ void gload_lds16(const unsigned short* g,
                                                   unsigned short* l) {
  __builtin_amdgcn_global_load_lds(
      (const __attribute__((address_space(1))) unsigned int*)g,
      (__attribute__((address_space(3))) unsigned int*)l, 16, 0, 0);
}

// ---------------- GEMM: C[M,N] = A[M,K] * B[N,K]^T ----------------
template <int MODE>
__global__ __launch_bounds__(256) void gemm_bt(
    const unsigned short* __restrict__ A,
    const unsigned short* __restrict__ B,
    void* __restrict__ Cv,
    const float* __restrict__ bias) {
  __shared__ unsigned short As[128 * 32];
  __shared__ unsigned short Bs[128 * 32];
  const int t = threadIdx.x;
  const int lane = t & 63, wave = t >> 6;
  const int fr = lane & 15, fq = lane >> 4;
  const int m0 = blockIdx.x * 128, n0 = blockIdx.y * 128;
  const int wm0 = (wave >> 1) * 64, wn0 = (wave & 1) * 64;

  const int srow = wave * 16 + (lane >> 2);
  const int scol = (lane & 3) * 8;
  const unsigned short* gA = A + (size_t)(m0 + srow) * KD + scol;
  const unsigned short* gB = B + (size_t)(n0 + srow) * KD + scol;
  unsigned short* lA = &As[srow * 32 + scol];
  unsigned short* lB = &Bs[srow * 32 + scol];

  f32x4 acc[4][4];
#pragma unroll
  for (int i = 0; i < 4; ++i)
#pragma unroll
    for (int j = 0; j < 4; ++j) acc[i][j] = (f32x4){0.f, 0.f, 0.f, 0.f};

  for (int k0 = 0;;) {
    gload_lds16(gA + k0, lA);
    gload_lds16(gA + (size_t)64 * KD + k0, lA + 64 * 32);
    gload_lds16(gB + k0, lB);
    gload_lds16(gB + (size_t)64 * KD + k0, lB + 64 * 32);
    __syncthreads();

    bf16x8 af[4], bfv[4];
#pragma unroll
    for (int mi = 0; mi < 4; ++mi)
      af[mi] = *(const bf16x8*)&As[(wm0 + mi * 16 + fr) * 32 + fq * 8];
#pragma unroll
    for (int nj = 0; nj < 4; ++nj)
      bfv[nj] = *(const bf16x8*)&Bs[(wn0 + nj * 16 + fr) * 32 + fq * 8];
#pragma unroll
    for (int mi = 0; mi < 4; ++mi)
#pragma unroll
      for (int nj = 0; nj < 4; ++nj)
        acc[mi][nj] = __builtin_amdgcn_mfma_f32_16x16x32_bf16(
            af[mi], bfv[nj], acc[mi][nj], 0, 0, 0);

    k0 += 32;
    if (k0 >= KD) break;
    __syncthreads();
  }

#pragma unroll
  for (int mi = 0; mi < 4; ++mi)
#pragma unroll
    for (int nj = 0; nj < 4; ++nj)
#pragma unroll
      for (int r = 0; r < 4; ++r) {
        const int gr = m0 + wm0 + mi * 16 + fq * 4 + r;
        const int gc = n0 + wn0 + nj * 16 + fr;
        const float v = acc[mi][nj][r];
        if (MODE == 0) {
          size_t off = (((size_t)(gr >> 11) * HEADS + (gc >> 6)) * SEQ +
                        (gr & 2047)) * HDIM + (gc & 63);
          ((unsigned short*)Cv)[off] = f2bf(v);
        } else if (MODE == 1) {
          size_t off = (size_t)(gc >> 11) * (DIMV * SEQ) + (size_t)gr * SEQ +
                       (gc & 2047);
          ((unsigned short*)Cv)[off] = f2bf(v);
        } else {
          ((float*)Cv)[(size_t)gr * DIMV + gc] = v + bias[gc];
        }
      }
}

// ---------------- flash attention (LDS K/V dbuf, 16 q-rows/wave) ----------
// grid 1024: xcd = wg&7 owns 8 bh x 16 q-tiles -> K/V = 4MB, L2-fit.
// 8 waves x 16 q-rows = 128 rows/block; K,V staged once per block into
// double-buffered XOR-swizzled LDS. LDS = 16+16+8 = 40KB -> 3-4 blocks/CU.
// Swapped QK^T: lane holds S[q=fr][k=nj*16+fq*4+r] -> lane-local softmax.
// PV = mfma(P, V) interleaved per 32-key chunk: O[q=fq*4+r][d=dj*16+fr].
__global__ __launch_bounds__(512, 6) void attn_kernel(
    const unsigned short* __restrict__ q, const unsigned short* __restrict__ k,
    const unsigned short* __restrict__ vt, unsigned short* __restrict__ ao) {
  __shared__ unsigned short Ks[2][64 * 64];  // 16 KB, swizzled rows
  __shared__ unsigned short Vs[2][64 * 64];  // 16 KB, swizzled rows
  __shared__ unsigned short Pl[8][16 * 32];  // 8 KB: per-wave 32-key P chunk
  const int t = threadIdx.x, lane = t & 63, wave = t >> 6;
  const int fr = lane & 15, fq = lane >> 4;
  const int wg = blockIdx.x;
  const int xcd = wg & 7, idx = wg >> 3;
  const int bh = (xcd << 3) | (idx >> 4);   // 8 bh per XCD
  const int qt = idx & 15;                  // 16 q-tiles of 128 rows
  const int b = bh >> 4, h = bh & 15;
  const int qrow0 = qt * 128 + wave * 16;

  const unsigned short* qp = q + ((size_t)bh * SEQ + qrow0) * HDIM;
  const unsigned short* kp = k + (size_t)bh * SEQ * HDIM;
  const unsigned short* vp = vt + (size_t)b * (DIMV * SEQ) + (size_t)(h * HDIM) * SEQ;
  char* plw = (char*)&Pl[wave][0];

  // staging: thread t covers LDS bytes [t*16, t*16+16) of an 8KB tile.
  // LDS[row][c] holds global[row][c ^ ((row&7)<<4)] (read-side XOR applied).
  const int srow = t >> 3;
  const int scolb = ((t & 7) << 4) ^ ((srow & 7) << 4);

  bf16x8 qf[2];
#pragma unroll
  for (int kc = 0; kc < 2; ++kc)
    qf[kc] = *(const bf16x8*)(qp + (size_t)fr * HDIM + kc * 32 + fq * 8);

  f32x4 oacc[4];
#pragma unroll
  for (int dj = 0; dj < 4; ++dj) oacc[dj] = (f32x4){0.f, 0.f, 0.f, 0.f};
  float m_s = -1e30f, lrow = 0.f;
  float m_o[4];
#pragma unroll
  for (int r = 0; r < 4; ++r) m_o[r] = -1e30f;

  // prologue: stage tile 0
  gload_lds16(kp + (size_t)srow * HDIM + (scolb >> 1), &Ks[0][t * 8]);
  gload_lds16(vp + (size_t)srow * SEQ + (scolb >> 1), &Vs[0][t * 8]);
  __syncthreads();

  int cur = 0;
  for (int kb = 0; kb < SEQ; kb += 64, cur ^= 1) {
    if (kb + 64 < SEQ) {
      gload_lds16(kp + (size_t)(kb + 64 + srow) * HDIM + (scolb >> 1),
                  &Ks[cur ^ 1][t * 8]);
      gload_lds16(vp + (size_t)srow * SEQ + (kb + 64) + (scolb >> 1),
                  &Vs[cur ^ 1][t * 8]);
    }

    const char* kls = (const char*)&Ks[cur][0];
    const char* vls = (const char*)&Vs[cur][0];

    // ---- S = mfma(K, Q): lane holds S[q=fr][k=nj*16+fq*4+r] ----
    f32x4 sacc[4];
#pragma unroll
    for (int nj = 0; nj < 4; ++nj) sacc[nj] = (f32x4){0.f, 0.f, 0.f, 0.f};
#pragma unroll
    for (int kc = 0; kc < 2; ++kc) {
      bf16x8 kf[4];
#pragma unroll
      for (int nj = 0; nj < 4; ++nj)
        kf[nj] = *(const bf16x8*)(kls + (nj * 16 + fr) * 128 +
                                  ((kc * 64 + fq * 16) ^ ((fr & 7) << 4)));
      __builtin_amdgcn_s_setprio(1);
#pragma unroll
      for (int nj = 0; nj < 4; ++nj)
        sacc[nj] = __builtin_amdgcn_mfma_f32_16x16x32_bf16(
            kf[nj], qf[kc], sacc[nj], 0, 0, 0);
      __builtin_amdgcn_s_setprio(0);
    }

    // ---- online softmax, lane-local per q-row ----
    float t0 = fmaxf(fmaxf(sacc[0][0], sacc[0][1]), fmaxf(sacc[0][2], sacc[0][3]));
    float t1 = fmaxf(fmaxf(sacc[1][0], sacc[1][1]), fmaxf(sacc[1][2], sacc[1][3]));
    float t2 = fmaxf(fmaxf(sacc[2][0], sacc[2][1]), fmaxf(sacc[2][2], sacc[2][3]));
    float t3 = fmaxf(fmaxf(sacc[3][0], sacc[3][1]), fmaxf(sacc[3][2], sacc[3][3]));
    float tmax = fmaxf(fmaxf(t0, t1), fmaxf(t2, t3));
    tmax = fmaxf(tmax, __shfl_xor(tmax, 16));
    tmax = fmaxf(tmax, __shfl_xor(tmax, 32));

    if (__any(tmax > m_s + THRRAW)) {   // defer-max (T13)
      const float mnew = fmaxf(m_s, tmax);
      lrow *= exp2f((m_s - mnew) * SCL);
      m_s = mnew;
#pragma unroll
      for (int r = 0; r < 4; ++r) {
        const float t_o = __shfl(tmax, ((lane >> 4) << 2) + r);
        const float mo_new = fmaxf(m_o[r], t_o);
        const float fo = exp2f((m_o[r] - mo_new) * SCL);
        m_o[r] = mo_new;
#pragma unroll
        for (int dj = 0; dj < 4; ++dj) oacc[dj][r] *= fo;
      }
    }

    // ---- per-32-key chunk: exp + P-write + PV (Pl holds one chunk) ----
    const float nm = m_s * SCL;
#pragma unroll
    for (int kc = 0; kc < 2; ++kc) {
#pragma unroll
      for (int nj = kc * 2; nj < kc * 2 + 2; ++nj) {
        float p0 = exp2f(__builtin_fmaf(sacc[nj][0], SCL, -nm));
        float p1 = exp2f(__builtin_fmaf(sacc[nj][1], SCL, -nm));
        float p2 = exp2f(__builtin_fmaf(sacc[nj][2], SCL, -nm));
        float p3 = exp2f(__builtin_fmaf(sacc[nj][3], SCL, -nm));
        lrow += (p0 + p1) + (p2 + p3);
        const int colb = (nj & 1) * 32 + fq * 8;
        *(uint2*)(plw + ((fr * 64 + colb) ^ ((fr & 3) << 4))) =
            make_uint2(pk2(p0, p1), pk2(p2, p3));
      }
      bf16x8 pf = *(const bf16x8*)(plw + ((fr * 64 + fq * 16) ^ ((fr & 3) << 4)));
      bf16x8 vf[4];
#pragma unroll
      for (int dj = 0; dj < 4; ++dj)
        vf[dj] = *(const bf16x8*)(vls + (dj * 16 + fr) * 128 +
                                  ((kc * 64 + fq * 16) ^ ((fr & 7) << 4)));
      __builtin_amdgcn_s_setprio(1);
#pragma unroll
      for (int dj = 0; dj < 4; ++dj)
        oacc[dj] = __builtin_amdgcn_mfma_f32_16x16x32_bf16(
            pf, vf[dj], oacc[dj], 0, 0, 0);
      __builtin_amdgcn_s_setprio(0);
    }

    __syncthreads();  // next tile staged; all reads of Ks/Vs[cur] done
  }

  // ---- final l reduce + redistribute to O-layout, normalize + store ----
  float lt = lrow;
  lt += __shfl_xor(lt, 16);
  lt += __shfl_xor(lt, 32);
#pragma unroll
  for (int r = 0; r < 4; ++r) {
    const float l_o = __shfl(lt, ((lane >> 4) << 2) + r);
    const float inv = 1.f / l_o;
    const size_t grow = (size_t)b * SEQ + qt * 128 + wave * 16 + fq * 4 + r;
#pragma unroll
    for (int dj = 0; dj < 4; ++dj) {
      const int col = h * HDIM + dj * 16 + fr;
      ao[grow * DIMV + col] = bfc(oacc[dj][r] * inv);
    }
  }
}

// ---------------- launch ----------------
extern "C" void kernel_launch(void* const* d_in, const int* in_sizes, int n_in,
                              void* d_out, int out_size, void* d_ws, size_t ws_size,
                              hipStream_t stream) {
  const float* x   = (const float*)d_in[0];
  const float* ctx = (const float*)d_in[1];
  const float* Wq  = (const float*)d_in[2];
  const float* Wk  = (const float*)d_in[3];
  const float* Wv  = (const float*)d_in[4];
  const float* Wo  = (const float*)d_in[5];
  const float* bo  = (const float*)d_in[6];

  char* ws = (char*)d_ws;
  unsigned short* xb  = (unsigned short*)(ws);              // 16MB, reused as ao
  unsigned short* cb  = (unsigned short*)(ws + 16777216);   // 16MB
  unsigned short* wqb = (unsigned short*)(ws + 33554432);   // 2MB
  unsigned short* wkb = (unsigned short*)(ws + 35651584);
  unsigned short* wvb = (unsigned short*)(ws + 37748736);
  unsigned short* wob = (unsigned short*)(ws + 39845888);
  unsigned short* qb  = (unsigned short*)(ws + 41943040);   // 16MB
  unsigned short* kb  = (unsigned short*)(ws + 58720256);   // 16MB
  unsigned short* vtb = (unsigned short*)(ws + 75497472);   // 16MB

  auto cvt = [&](const float* s, unsigned short* d, int n) {
    int n4 = n >> 2;
    cvt_kernel<<<(n4 + 255) / 256, 256, 0, stream>>>(s, (ushort4*)d, n4);
  };
  const int NTOK = 4 * SEQ;  // 8192
  cvt(x,   xb,  NTOK * DIMV);
  cvt(ctx, cb,  NTOK * DIMV);
  cvt(Wq,  wqb, DIMV * DIMV);
  cvt(Wk,  wkb, DIMV * DIMV);
  cvt(Wv,  wvb, DIMV * DIMV);
  cvt(Wo,  wob, DIMV * DIMV);

  gemm_bt<0><<<dim3(64, 8), 256, 0, stream>>>(xb, wqb, qb, nullptr);
  gemm_bt<0><<<dim3(64, 8), 256, 0, stream>>>(cb, wkb, kb, nullptr);
  gemm_bt<1><<<dim3(8, 64), 256, 0, stream>>>(wvb, cb, vtb, nullptr);

  unsigned short* aob = xb;
  attn_kernel<<<dim3(1024), 512, 0, stream>>>(qb, kb, vtb, aob);

  gemm_bt<2><<<dim3(64, 8), 256, 0, stream>>>(aob, wob, (float*)d_out, bo);
}